// Round 9
// baseline (148.811 us; speedup 1.0000x reference)
//
#include <hip/hip_runtime.h>
#include <math.h>

// GenSP: SSN superpixels, x(1,64,384,384), stoken=16.
// S=576 superpixels (24x24 grid of 16x16 px blocks), C=64, P=147456, N_ITER=3.
// f64 label chain (R1/R3/R4/R6 bit-matched np f64 ref, absmax 0.0).
// R8: 256-thread heavy blocks (4 waves = 4 channel-quarters via
// readfirstlane -> SGPR -> cent stays on the scalar pipe; R5's taint fixed),
// pdot combine in LDS, aff overlaid on dead pdot, x staged once in stride-65
// LDS for the dot phase. 20 waves/CU vs R6's 9.

#define NC   64
#define IMW  384
#define HWP  (384*384)
#define NSH  24
#define NSW  24
#define NS   (NSH*NSW)
#define NBG  (NS*4)       // 2304 chunk-blocks (4 x 64px per superpixel block)

// ---- K1a: per-chunk partial sums for initial centroids (validated R4) -----
__global__ __launch_bounds__(256) void k_cent_part(const float* __restrict__ x,
                                                   double* __restrict__ centp) {
    int bg = blockIdx.x, b = bg >> 2, g = bg & 3;
    int by = b / NSW, bx = b % NSW;
    int t = threadIdx.x, q = t >> 2, r = t & 3;
    const float* gp = x + (size_t)q * HWP + (size_t)(by * 16 + g * 4) * IMW + bx * 16 + r * 4;
    double s = 0.0;
    #pragma unroll
    for (int j = 0; j < 4; ++j) {
        float4 v = *(const float4*)(gp + (size_t)j * IMW);
        s += (double)v.x; s += (double)v.y; s += (double)v.z; s += (double)v.w;
    }
    s += __shfl_xor(s, 1, 64);
    s += __shfl_xor(s, 2, 64);
    if (r == 0) centp[(size_t)bg * NC + q] = s;
}

// ---- K1b: reduce 4 chunk partials -> initial cent + cnorm -----------------
__global__ __launch_bounds__(64) void k_cent_red(const double* __restrict__ centp,
                                                 double* __restrict__ cent,
                                                 double* __restrict__ cnorm) {
    int s = blockIdx.x, c = threadIdx.x;
    double v = centp[(size_t)(s * 4 + 0) * NC + c] + centp[(size_t)(s * 4 + 1) * NC + c]
             + centp[(size_t)(s * 4 + 2) * NC + c] + centp[(size_t)(s * 4 + 3) * NC + c];
    v *= (1.0 / 256.0);
    cent[s * NC + c] = v;
    double n2 = v * v;
    #pragma unroll
    for (int off = 32; off >= 1; off >>= 1) n2 += __shfl_down(n2, off, 64);
    if (c == 0) cnorm[s] = n2;
}

// ---- K2: soft iteration ---------------------------------------------------
__global__ __launch_bounds__(256, 5) void k_iter(const float* __restrict__ x,
        const double* __restrict__ cent, const double* __restrict__ cnorm,
        double* __restrict__ bnum, double* __restrict__ bden) {
    int bg = blockIdx.x, b = bg >> 2, g = bg & 3;
    int by = b / NSW, bx = b % NSW;
    int t = threadIdx.x;
    int p = t & 63;                                       // pixel in 64px chunk
    int q = __builtin_amdgcn_readfirstlane(t >> 6);       // wave id 0..3 (SGPR)

    __shared__ float  xb[64 * 65];        // 16640 B, stride 65 -> conflict-free
    __shared__ double pdot_aff[3 * 9 * 64];   // 13824 B; aff[64][10] overlays later
    double* pdot = pdot_aff;
    double* aff  = pdot_aff;              // [p*10 + k], live after pdot consumed

    int cand[9]; bool vld[9];
    #pragma unroll
    for (int k = 0; k < 9; ++k) {         // pure blockIdx math -> SGPR
        int cy = by + k / 3 - 1, cx = bx + k % 3 - 1;
        vld[k] = (cy >= 0) && (cy < NSH) && (cx >= 0) && (cx < NSW);
        cand[k] = vld[k] ? (cy * NSW + cx) : 0;
    }

    // distance partial over channels c = q*16 .. q*16+15 (cent via s_load)
    const float* xp = x + (size_t)(by * 16 + g * 4 + (p >> 4)) * IMW + bx * 16 + (p & 15);
    double dot[9] = {0, 0, 0, 0, 0, 0, 0, 0, 0};
    #pragma unroll
    for (int i = 0; i < 16; ++i) {
        int c = q * 16 + i;                               // SGPR
        float xf = xp[(size_t)c * HWP];
        xb[p * 65 + c] = xf;                              // stage for dot phase
        double xv = (double)xf;
        #pragma unroll
        for (int k = 0; k < 9; ++k)
            dot[k] = fma(xv, cent[(size_t)cand[k] * NC + c], dot[k]);
    }
    if (q) {
        #pragma unroll
        for (int k = 0; k < 9; ++k) pdot[((q - 1) * 9 + k) * 64 + p] = dot[k];
    }
    __syncthreads();

    if (q == 0) {                          // softmax, wave 0, lane = pixel
        double d[9], m = -1e300;
        #pragma unroll
        for (int k = 0; k < 9; ++k) {
            double dt = dot[k] + pdot[(0 * 9 + k) * 64 + p]
                               + pdot[(1 * 9 + k) * 64 + p]
                               + pdot[(2 * 9 + k) * 64 + p];
            d[k] = fma(dt, -2.0, cnorm[cand[k]]);
            if (vld[k]) m = fmax(m, -d[k]);
        }
        double e[9], ss = 0.0;
        #pragma unroll
        for (int k = 0; k < 9; ++k) { e[k] = vld[k] ? exp(-d[k] - m) : 0.0; ss += e[k]; }
        double inv = 1.0 / ss;
        #pragma unroll
        for (int k = 0; k < 9; ++k) { e[k] *= inv; aff[p * 10 + k] = e[k]; }
        // pdot reads precede aff writes in wave-0 program order -> overlay safe
        #pragma unroll
        for (int k = 0; k < 9; ++k) {      // den per (chunk,k), R6 reduce order
            double dn = e[k];
            #pragma unroll
            for (int off = 32; off >= 1; off >>= 1) dn += __shfl_down(dn, off, 64);
            if (p == 0) bden[(size_t)bg * 9 + k] = dn;
        }
    }
    __syncthreads();

    // dot phase: thread (c = t&63, kq) -> k = 2kq, 2kq+1 (+8 on wave 0)
    int c = t & 63, kq = t >> 6;
    int k0 = 2 * kq;
    double a0 = 0, a1 = 0, a2 = 0;
    for (int pp = 0; pp < 64; ++pp) {
        double xd = (double)xb[pp * 65 + c];
        double2 av = *(const double2*)&aff[pp * 10 + k0];   // 16B-aligned broadcast
        a0 = fma(av.x, xd, a0);
        a1 = fma(av.y, xd, a1);
        if (kq == 0) a2 = fma(aff[pp * 10 + 8], xd, a2);
    }
    bnum[((size_t)bg * 9 + k0) * NC + c] = a0;
    bnum[((size_t)bg * 9 + k0 + 1) * NC + c] = a1;
    if (kq == 0) bnum[((size_t)bg * 9 + 8) * NC + c] = a2;
}

// ---- K3: centroid update: gather 9k x 4g partials -> cent + cnorm ---------
__global__ __launch_bounds__(64) void k_gather_cent(const double* __restrict__ bnum,
                                                    const double* __restrict__ bden,
                                                    double* __restrict__ cent,
                                                    double* __restrict__ cnorm) {
    int s = blockIdx.x, c = threadIdx.x;
    int sy = s / NSW, sx = s % NSW;
    double num = 0.0, den = 0.0;
    #pragma unroll
    for (int k = 0; k < 9; ++k) {
        int by2 = sy - (k / 3 - 1), bx2 = sx - (k % 3 - 1);
        if (by2 >= 0 && by2 < NSH && bx2 >= 0 && bx2 < NSW) {
            int b2 = by2 * NSW + bx2;
            #pragma unroll
            for (int g = 0; g < 4; ++g) {
                int bg = b2 * 4 + g;
                num += bnum[((size_t)bg * 9 + k) * NC + c];
                den += bden[(size_t)bg * 9 + k];
            }
        }
    }
    double v = num / (den + 1e-16);
    cent[s * NC + c] = v;
    double n2 = v * v;
    #pragma unroll
    for (int off = 32; off >= 1; off >>= 1) n2 += __shfl_down(n2, off, 64);
    if (c == 0) cnorm[s] = n2;
}

// ---- K4: final: argmin labels + hard-label partial sums -------------------
__global__ __launch_bounds__(256, 5) void k_final(const float* __restrict__ x,
        const double* __restrict__ cent, const double* __restrict__ cnorm,
        int* __restrict__ labels,
        double* __restrict__ bnum, double* __restrict__ bden) {
    int bg = blockIdx.x, b = bg >> 2, g = bg & 3;
    int by = b / NSW, bx = b % NSW;
    int t = threadIdx.x;
    int p = t & 63;
    int q = __builtin_amdgcn_readfirstlane(t >> 6);

    __shared__ float  xb[64 * 65];
    __shared__ double pdot_aff[3 * 9 * 64];
    double* pdot = pdot_aff;
    int* ibk = (int*)pdot_aff;            // overlays dead pdot after combine

    int cand[9]; bool vld[9];
    #pragma unroll
    for (int k = 0; k < 9; ++k) {
        int cy = by + k / 3 - 1, cx = bx + k % 3 - 1;
        vld[k] = (cy >= 0) && (cy < NSH) && (cx >= 0) && (cx < NSW);
        cand[k] = vld[k] ? (cy * NSW + cx) : 0;
    }

    const float* xp = x + (size_t)(by * 16 + g * 4 + (p >> 4)) * IMW + bx * 16 + (p & 15);
    double dot[9] = {0, 0, 0, 0, 0, 0, 0, 0, 0};
    #pragma unroll
    for (int i = 0; i < 16; ++i) {
        int c = q * 16 + i;
        float xf = xp[(size_t)c * HWP];
        xb[p * 65 + c] = xf;
        double xv = (double)xf;
        #pragma unroll
        for (int k = 0; k < 9; ++k)
            dot[k] = fma(xv, cent[(size_t)cand[k] * NC + c], dot[k]);
    }
    if (q) {
        #pragma unroll
        for (int k = 0; k < 9; ++k) pdot[((q - 1) * 9 + k) * 64 + p] = dot[k];
    }
    __syncthreads();

    if (q == 0) {
        double bestd = 1e300; int bk = 0;
        #pragma unroll
        for (int k = 0; k < 9; ++k) {
            double dt = dot[k] + pdot[(0 * 9 + k) * 64 + p]
                               + pdot[(1 * 9 + k) * 64 + p]
                               + pdot[(2 * 9 + k) * 64 + p];
            double dv = fma(dt, -2.0, cnorm[cand[k]]);
            if (vld[k] && dv < bestd) { bestd = dv; bk = k; }   // first-wins
        }
        ibk[p] = bk;                       // pdot reads precede this write
        labels[(size_t)(by * 16 + g * 4 + (p >> 4)) * IMW + bx * 16 + (p & 15)] =
            (by + bk / 3 - 1) * NSW + (bx + bk % 3 - 1);
        #pragma unroll
        for (int k = 0; k < 9; ++k) {      // counts per (chunk,k)
            int cnt = (bk == k);
            #pragma unroll
            for (int off = 32; off >= 1; off >>= 1) cnt += __shfl_down(cnt, off, 64);
            if (p == 0) bden[(size_t)bg * 9 + k] = (double)cnt;
        }
    }
    __syncthreads();

    int c = t & 63, kq = t >> 6;
    int k0 = 2 * kq;
    double a0 = 0, a1 = 0, a2 = 0;
    for (int pp = 0; pp < 64; ++pp) {
        int bkp = ibk[pp];                 // uniform broadcast b32
        double xd = (double)xb[pp * 65 + c];
        a0 += (bkp == k0) ? xd : 0.0;
        a1 += (bkp == k0 + 1) ? xd : 0.0;
        if (kq == 0) a2 += (bkp == 8) ? xd : 0.0;
    }
    bnum[((size_t)bg * 9 + k0) * NC + c] = a0;
    bnum[((size_t)bg * 9 + k0 + 1) * NC + c] = a1;
    if (kq == 0) bnum[((size_t)bg * 9 + 8) * NC + c] = a2;
}

// ---- K5: gather paint sums -> per-superpixel channel means (f32) ----------
__global__ __launch_bounds__(64) void k_means_(const double* __restrict__ bnum,
                                               const double* __restrict__ bden,
                                               float* __restrict__ means) {
    int s = blockIdx.x, c = threadIdx.x;
    int sy = s / NSW, sx = s % NSW;
    double num = 0.0, den = 0.0;
    #pragma unroll
    for (int k = 0; k < 9; ++k) {
        int by2 = sy - (k / 3 - 1), bx2 = sx - (k % 3 - 1);
        if (by2 >= 0 && by2 < NSH && bx2 >= 0 && bx2 < NSW) {
            int b2 = by2 * NSW + bx2;
            #pragma unroll
            for (int g = 0; g < 4; ++g) {
                int bg = b2 * 4 + g;
                num += bnum[((size_t)bg * 9 + k) * NC + c];
                den += bden[(size_t)bg * 9 + k];
            }
        }
    }
    means[s * NC + c] = (float)(num / fmax(den, 1.0));
}

// ---- K6: paint out[c][p] = means[lab[p]][c]; 4 px x 4 ch per thread -------
__global__ __launch_bounds__(256) void k_paint(const int* __restrict__ labels,
                                               const float* __restrict__ means,
                                               float* __restrict__ out) {
    int p0 = (blockIdx.x * 256 + threadIdx.x) * 4;
    int4 lb = *(const int4*)&labels[p0];
    int c0 = blockIdx.y * 4;
    #pragma unroll
    for (int j = 0; j < 4; ++j) {
        int c = c0 + j;
        float4 o;
        o.x = means[lb.x * NC + c];
        o.y = means[lb.y * NC + c];
        o.z = means[lb.z * NC + c];
        o.w = means[lb.w * NC + c];
        *(float4*)&out[(size_t)c * HWP + p0] = o;
    }
}

extern "C" void kernel_launch(void* const* d_in, const int* in_sizes, int n_in,
                              void* d_out, int out_size, void* d_ws, size_t ws_size,
                              hipStream_t stream) {
    const float* x = (const float*)d_in[0];
    float* out = (float*)d_out;
    char* ws = (char*)d_ws;
    char* od = (char*)d_out;

    constexpr size_t CENTP_B = (size_t)NBG * NC * 8;      // 1179648
    constexpr size_t CENT_B  = (size_t)NS * NC * 8;       // 294912 (x2)
    constexpr size_t CNRM_B  = (size_t)NS * 8;            // 4608   (x2)
    constexpr size_t BNUM_B  = (size_t)NBG * 9 * NC * 8;  // 10616832
    constexpr size_t BDEN_B  = (size_t)NBG * 9 * 8;       // 165888
    constexpr size_t LAB_B   = (size_t)HWP * 4;           // 589824
    constexpr size_t MEANS_B = (size_t)NS * NC * 4;       // 147456
    constexpr size_t T_PAINT = LAB_B + MEANS_B;           // must live in ws
    constexpr size_t T_CENT  = T_PAINT + 2 * (CENT_B + CNRM_B);
    constexpr size_t T_ALL   = T_CENT + CENTP_B + BNUM_B + BDEN_B;

    int* labels = (int*)ws;
    float* means = (float*)(ws + LAB_B);
    double *centA, *centB, *cnormA, *cnormB, *centp, *bnum, *bden;
    if (ws_size >= T_ALL) {
        centA  = (double*)(ws + T_PAINT);
        centB  = (double*)(ws + T_PAINT + CENT_B);
        cnormA = (double*)(ws + T_PAINT + 2 * CENT_B);
        cnormB = (double*)(ws + T_PAINT + 2 * CENT_B + CNRM_B);
        centp  = (double*)(ws + T_CENT);
        bnum   = (double*)(ws + T_CENT + CENTP_B);
        bden   = (double*)(ws + T_CENT + CENTP_B + BNUM_B);
    } else if (ws_size >= T_CENT) {
        centA  = (double*)(ws + T_PAINT);
        centB  = (double*)(ws + T_PAINT + CENT_B);
        cnormA = (double*)(ws + T_PAINT + 2 * CENT_B);
        cnormB = (double*)(ws + T_PAINT + 2 * CENT_B + CNRM_B);
        centp  = (double*)od;
        bnum   = (double*)(od + CENTP_B);
        bden   = (double*)(od + CENTP_B + BNUM_B);
    } else {
        centp  = (double*)od;
        bnum   = (double*)(od + CENTP_B);
        bden   = (double*)(od + CENTP_B + BNUM_B);
        centA  = (double*)(od + CENTP_B + BNUM_B + BDEN_B);
        centB  = (double*)(od + CENTP_B + BNUM_B + BDEN_B + CENT_B);
        cnormA = (double*)(od + CENTP_B + BNUM_B + BDEN_B + 2 * CENT_B);
        cnormB = (double*)(od + CENTP_B + BNUM_B + BDEN_B + 2 * CENT_B + CNRM_B);
    }
    // all d_out-resident scratch is consumed before k_paint overwrites d_out

    k_cent_part<<<NBG, 256, 0, stream>>>(x, centp);
    k_cent_red<<<NS, 64, 0, stream>>>(centp, centA, cnormA);
    k_iter<<<NBG, 256, 0, stream>>>(x, centA, cnormA, bnum, bden);
    k_gather_cent<<<NS, 64, 0, stream>>>(bnum, bden, centB, cnormB);
    k_iter<<<NBG, 256, 0, stream>>>(x, centB, cnormB, bnum, bden);
    k_gather_cent<<<NS, 64, 0, stream>>>(bnum, bden, centA, cnormA);
    k_final<<<NBG, 256, 0, stream>>>(x, centA, cnormA, labels, bnum, bden);
    k_means_<<<NS, 64, 0, stream>>>(bnum, bden, means);
    k_paint<<<dim3(HWP / 1024, NC / 4), 256, 0, stream>>>(labels, means, out);
}